// Round 7
// baseline (266.688 us; speedup 1.0000x reference)
//
#include <hip/hip_runtime.h>
#include <hip/hip_bf16.h>
#include <math.h>

// B=2, S=2048, D=2048, H=16, KV=4, HD=128, n_rep=4
// qkv layout per row (b*2048+s): [0,2048) q | [2048,2560) k  (v goes straight to vt)
// wqkv is column-PERMUTED for q/k heads: head-local col c holds orig d = (c>>1)+((c&1)<<6)
// Q is scaled by (1/sqrt(128))*log2(e): flash softmax runs in exp2 domain.

typedef __attribute__((ext_vector_type(4))) float f32x4;
typedef __attribute__((ext_vector_type(8))) short short8;
typedef __attribute__((ext_vector_type(4))) unsigned short u16x4;
typedef __attribute__((ext_vector_type(8))) unsigned short u16x8;

static __device__ __forceinline__ unsigned short f2bf(float x) {
    unsigned u = __builtin_bit_cast(unsigned, x);
    u += 0x7fffu + ((u >> 16) & 1u);          // RNE
    return (unsigned short)(u >> 16);
}
static __device__ __forceinline__ float exp2_fast(float x) {
    float r;
    asm volatile("v_exp_f32 %0, %1" : "=v"(r) : "v"(x));
    return r;
}
static __device__ __forceinline__ void gload16(const unsigned short* g, unsigned short* lds) {
    __builtin_amdgcn_global_load_lds((const __attribute__((address_space(1))) void*)g,
                                     (__attribute__((address_space(3))) void*)lds, 16, 0, 0);
}

// ---------------- fused prep: hs->bf16 | wqkv permuted concat | wo->bf16 | rope table ----
__global__ __launch_bounds__(256) void k_prep(const float* __restrict__ hs,
                                              const float* __restrict__ wq,
                                              const float* __restrict__ wk,
                                              const float* __restrict__ wv,
                                              const float* __restrict__ wo,
                                              const int* __restrict__ pos_ids,
                                              unsigned short* __restrict__ hsb,
                                              unsigned short* __restrict__ wqkvb,
                                              unsigned short* __restrict__ wob,
                                              float2* __restrict__ tb) {
    long idx = (long)blockIdx.x * 256 + threadIdx.x;
    if (idx < 2097152) {                       // hs -> bf16
        f32x4 v = ((const f32x4*)hs)[idx];
        u16x4 o;
        o.x = f2bf(v.x); o.y = f2bf(v.y); o.z = f2bf(v.z); o.w = f2bf(v.w);
        ((u16x4*)hsb)[idx] = o;
    } else if (idx < 3670016) {                // wqkv concat (q/k col-permuted)
        long i = idx - 2097152;
        long flat = i * 4;
        int row = (int)(flat >> 11);
        int col = (int)(flat & 2047);
        const float* src;
        if (row < 2560) {
            int base = row & 2047;
            int hh = base >> 7, ii = base & 127;
            int d = (ii >> 1) + ((ii & 1) << 6);
            src = (row < 2048 ? wq : wk) + (size_t)(hh * 128 + d) * 2048;
        } else {
            src = wv + (size_t)(row - 2560) * 2048;
        }
        f32x4 v = *(const f32x4*)(src + col);
        u16x4 o;
        o.x = f2bf(v.x); o.y = f2bf(v.y); o.z = f2bf(v.z); o.w = f2bf(v.w);
        *(u16x4*)(wqkvb + flat) = o;
    } else if (idx < 4718592) {                // wo -> bf16
        long i = idx - 3670016;
        f32x4 v = ((const f32x4*)wo)[i];
        u16x4 o;
        o.x = f2bf(v.x); o.y = f2bf(v.y); o.z = f2bf(v.z); o.w = f2bf(v.w);
        ((u16x4*)wob)[i] = o;
    } else {                                   // rope table
        long j = idx - 4718592;                // [0, 262144)
        int r = (int)(j >> 6);
        int i = (int)(j & 63);
        float pos = (float)pos_ids[r];
        float powv = (float)pow(10000.0, (double)i / 64.0);
        float invf = 1.0f / powv;
        float arg  = pos * invf;
        double a = (double)arg;
        tb[(size_t)r * 64 + i] = make_float2((float)cos(a), (float)sin(a));
    }
}

// ---------------- 8-phase GEMM: C[M][N] = A[M][K] * W[N][K]^T ----------------
// BM=256, BK=64, 8 waves (2Mx4N). Double-buffered LDS, global_load_lds w16 staging
// with 8-slot XOR swizzle (slot ^= row&7), counted vmcnt(2) at phase 0 only.
// EPI 1: BN=256, fused QKV epilogue (RoPE q/k from permuted cols, V -> vt).
// EPI 0: BN=128, f32 store (O-proj).
template <int EPI>
__global__ __launch_bounds__(512, 2) void k_gemm8(const unsigned short* __restrict__ A,
                                                  const unsigned short* __restrict__ W,
                                                  float* __restrict__ Cf,
                                                  unsigned short* __restrict__ qkvt,
                                                  unsigned short* __restrict__ vtb,
                                                  const float2* __restrict__ tb,
                                                  int M, int N, int K) {
    constexpr int BN = EPI ? 256 : 128;
    constexpr int BHALF = BN / 128;            // B staging half-count
    __shared__ unsigned short As[2][16384];    // 256 rows x 64 cols
    __shared__ unsigned short Bs[2][BN * 64];
    const int tid = threadIdx.x;
    const int lane = tid & 63;
    const int w = tid >> 6;                    // 0..7
    const int q = lane & 15, g = lane >> 4;
    const int wr = w >> 2, wc = w & 3;

    // XCD swizzle (bijective: nwg % 8 == 0)
    const int nwg = gridDim.x * gridDim.y;
    const int id = blockIdx.y * gridDim.x + blockIdx.x;
    const int swz_id = (id & 7) * (nwg >> 3) + (id >> 3);
    const int bx = swz_id % gridDim.x;
    const int by = swz_id / gridDim.x;
    const long mbase = (long)by * 256;
    const long nbase = (long)bx * BN;

    // staging source pointers (pre-swizzled global addresses)
    const int lr = lane >> 3;                  // row within 8-row chunk
    const int lslot = (lane & 7) ^ lr;         // logical col slot
    const unsigned short* pA[2][2];
    const unsigned short* pB[BHALF][2];
    #pragma unroll
    for (int h = 0; h < 2; ++h)
        #pragma unroll
        for (int j = 0; j < 2; ++j)
            pA[h][j] = A + (size_t)(mbase + h * 128 + w * 16 + j * 8 + lr) * K + lslot * 8;
    #pragma unroll
    for (int h = 0; h < BHALF; ++h)
        #pragma unroll
        for (int j = 0; j < 2; ++j)
            pB[h][j] = W + (size_t)(nbase + h * 128 + w * 16 + j * 8 + lr) * K + lslot * 8;

    auto ISSUE_A = [&](int buf, int h) {
        gload16(pA[h][0], &As[buf][h * 8192 + w * 1024]);
        gload16(pA[h][1], &As[buf][h * 8192 + w * 1024 + 512]);
        pA[h][0] += 64; pA[h][1] += 64;
    };
    auto ISSUE_B = [&](int buf, int h) {
        gload16(pB[h][0], &Bs[buf][h * 8192 + w * 1024]);
        gload16(pB[h][1], &Bs[buf][h * 8192 + w * 1024 + 512]);
        pB[h][0] += 64; pB[h][1] += 64;
    };

    const int xs = q & 7;
    const int sl0 = (g ^ xs) * 8;              // k2=0 slot offset (shorts)
    const int sl1 = ((4 + g) ^ xs) * 8;        // k2=1

    const int NT = K >> 6;

    if constexpr (EPI == 1) {
        f32x4 acc[8][4];
        #pragma unroll
        for (int m = 0; m < 8; ++m)
            #pragma unroll
            for (int n = 0; n < 4; ++n) acc[m][n] = (f32x4){0.f, 0.f, 0.f, 0.f};
        short8 a[4][2], bq[2][2];

        auto loadA = [&](int cur, int mh) {
            #pragma unroll
            for (int mq = 0; mq < 4; ++mq) {
                int r = (wr * 128 + mh * 64 + mq * 16 + q) * 64;
                a[mq][0] = *(const short8*)&As[cur][r + sl0];
                a[mq][1] = *(const short8*)&As[cur][r + sl1];
            }
        };
        auto loadB = [&](int cur, int nh) {
            #pragma unroll
            for (int nq = 0; nq < 2; ++nq) {
                int r = (wc * 64 + nh * 32 + nq * 16 + q) * 64;
                bq[nq][0] = *(const short8*)&Bs[cur][r + sl0];
                bq[nq][1] = *(const short8*)&Bs[cur][r + sl1];
            }
        };
        auto mm = [&](int mh, int nh) {
            __builtin_amdgcn_s_setprio(1);
            #pragma unroll
            for (int mq = 0; mq < 4; ++mq)
                #pragma unroll
                for (int nq = 0; nq < 2; ++nq) {
                    f32x4 c = acc[mh * 4 + mq][nh * 2 + nq];
                    c = __builtin_amdgcn_mfma_f32_16x16x32_bf16(a[mq][0], bq[nq][0], c, 0, 0, 0);
                    c = __builtin_amdgcn_mfma_f32_16x16x32_bf16(a[mq][1], bq[nq][1], c, 0, 0, 0);
                    acc[mh * 4 + mq][nh * 2 + nq] = c;
                }
            __builtin_amdgcn_s_setprio(0);
        };

        // prologue: stage tile 0
        ISSUE_A(0, 0); ISSUE_A(0, 1); ISSUE_B(0, 0); ISSUE_B(0, 1);
        for (int t = 0; t < NT; ++t) {
            const int cur = t & 1, nxt = cur ^ 1;
            const bool more = (t + 1 < NT);
            // phase 0: quadrant (0,0)
            if (more) { ISSUE_A(nxt, 0); asm volatile("s_waitcnt vmcnt(2)" ::: "memory"); }
            else      { asm volatile("s_waitcnt vmcnt(0)" ::: "memory"); }
            __builtin_amdgcn_s_barrier();
            loadA(cur, 0); loadB(cur, 0); mm(0, 0);
            __builtin_amdgcn_s_barrier();
            // phase 1: quadrant (1,0)
            if (more) ISSUE_A(nxt, 1);
            loadA(cur, 1); mm(1, 0);
            __builtin_amdgcn_s_barrier();
            // phase 2: quadrant (1,1)
            if (more) ISSUE_B(nxt, 0);
            loadB(cur, 1); mm(1, 1);
            __builtin_amdgcn_s_barrier();
            // phase 3: quadrant (0,1)
            if (more) ISSUE_B(nxt, 1);
            loadA(cur, 0); mm(0, 1);
            __builtin_amdgcn_s_barrier();
        }

        // fused QKV epilogue. bx<8: q heads 2bx+hh; bx 8-9: k; bx 10-11: v.
        const float scale = (bx < 8) ? 0.12751744f : 1.0f;   // (1/sqrt(128))*log2e
        const float sgn = (q & 1) ? 1.f : -1.f;
        #pragma unroll
        for (int m = 0; m < 8; ++m) {
            long row0 = mbase + wr * 128 + m * 16 + 4 * g;
            #pragma unroll
            for (int n = 0; n < 4; ++n) {
                int col256 = wc * 64 + n * 16 + q;
                int hh = col256 >> 7, c = col256 & 127;
                if (bx >= 10) {                  // V -> vt[(b*4+kv)*128+c][s]
                    int kv = (bx - 10) * 2 + hh;
                    int b = (int)(row0 >> 11), s0 = (int)(row0 & 2047);
                    u16x4 pk;
                    #pragma unroll
                    for (int rr = 0; rr < 4; ++rr) pk[rr] = f2bf(acc[m][n][rr]);
                    *(u16x4*)(vtb + (size_t)((b * 4 + kv) * 128 + c) * 2048 + s0) = pk;
                } else {                         // q/k: RoPE, un-permute on store
                    int dorig = (c >> 1) + ((c & 1) << 6);
                    long col = (bx < 8) ? (bx * 256 + hh * 128 + dorig)
                                        : (2048 + (bx - 8) * 256 + hh * 128 + dorig);
                    #pragma unroll
                    for (int rr = 0; rr < 4; ++rr) {
                        long row = row0 + rr;
                        float x = acc[m][n][rr];
                        float p = __shfl_xor(x, 1);
                        float2 cs = tb[row * 64 + (c >> 1)];
                        float y = (x * cs.x + sgn * (p * cs.y)) * scale;
                        qkvt[row * 3072 + col] = f2bf(y);
                    }
                }
            }
        }
    } else {
        // BN=128: 2 phases per K-tile (by k2), 16 MFMA each
        f32x4 acc[8][2];
        #pragma unroll
        for (int m = 0; m < 8; ++m)
            #pragma unroll
            for (int n = 0; n < 2; ++n) acc[m][n] = (f32x4){0.f, 0.f, 0.f, 0.f};
        short8 a[8], bq[2];

        auto phase = [&](int cur, int slx) {
            #pragma unroll
            for (int m = 0; m < 8; ++m)
                a[m] = *(const short8*)&As[cur][(wr * 128 + m * 16 + q) * 64 + slx];
            #pragma unroll
            for (int n = 0; n < 2; ++n)
                bq[n] = *(const short8*)&Bs[cur][(wc * 32 + n * 16 + q) * 64 + slx];
            __builtin_amdgcn_s_setprio(1);
            #pragma unroll
            for (int m = 0; m < 8; ++m)
                #pragma unroll
                for (int n = 0; n < 2; ++n)
                    acc[m][n] = __builtin_amdgcn_mfma_f32_16x16x32_bf16(a[m], bq[n], acc[m][n], 0, 0, 0);
            __builtin_amdgcn_s_setprio(0);
        };

        ISSUE_A(0, 0); ISSUE_A(0, 1); ISSUE_B(0, 0);
        for (int t = 0; t < NT; ++t) {
            const int cur = t & 1, nxt = cur ^ 1;
            const bool more = (t + 1 < NT);
            if (more) { ISSUE_A(nxt, 0); asm volatile("s_waitcnt vmcnt(2)" ::: "memory"); }
            else      { asm volatile("s_waitcnt vmcnt(0)" ::: "memory"); }
            __builtin_amdgcn_s_barrier();
            phase(cur, sl0);
            __builtin_amdgcn_s_barrier();
            if (more) { ISSUE_A(nxt, 1); ISSUE_B(nxt, 0); }
            phase(cur, sl1);
            __builtin_amdgcn_s_barrier();
        }

        #pragma unroll
        for (int m = 0; m < 8; ++m)
            #pragma unroll
            for (int n = 0; n < 2; ++n)
                #pragma unroll
                for (int rr = 0; rr < 4; ++rr) {
                    long row = mbase + wr * 128 + m * 16 + 4 * g + rr;
                    long col = nbase + wc * 32 + n * 16 + q;
                    Cf[row * N + col] = acc[m][n][rr];
                }
    }
}

// ---------------- Flash attention (known-good R4/R6 config) ----------------
__global__ __launch_bounds__(256, 2) void k_flash(const unsigned short* __restrict__ qkv,
                                                  const unsigned short* __restrict__ vt,
                                                  unsigned short* __restrict__ aout) {
    __shared__ unsigned short Ks[2][8192];   // 64 keys x 128 hd, dbuf
    __shared__ unsigned short Vs[2][8192];   // 128 d x 64 keys, dbuf
    __shared__ unsigned short Plds[4][1152]; // per-wave 16 x 72
    const int wg = blockIdx.x;
    const int kvg = wg & 7;            // b*4+kvh -> pinned per XCD
    const int inner = wg >> 3;         // 0..63
    const int h_in = inner & 3;
    const int qt = inner >> 2;         // 0..15
    const int b = kvg >> 2, kvh = kvg & 3;
    const int h = kvh * 4 + h_in;
    const int tid = threadIdx.x;
    const int w = tid >> 6, lane = tid & 63;
    const int q = lane & 15, g = lane >> 4;
    const int qrow = qt * 128 + w * 32;

    short8 qf[2][4];
    #pragma unroll
    for (int u = 0; u < 2; ++u) {
        const unsigned short* Qp = qkv + (size_t)(b * 2048 + qrow + u * 16 + q) * 3072 + h * 128 + g * 8;
        #pragma unroll
        for (int t = 0; t < 4; ++t) qf[u][t] = *(const short8*)(Qp + t * 32);
    }

    const unsigned short* Kbase = qkv + (size_t)(b * 2048) * 3072 + 2048 + kvh * 128;
    const unsigned short* Vbase = vt + (size_t)((b * 4 + kvh) * 128) * 2048;
    const unsigned short* gK[4];
    const unsigned short* gV[4];
    #pragma unroll
    for (int i = 0; i < 4; ++i) {
        int rowK = w * 16 + i * 4 + (lane >> 4);
        gK[i] = Kbase + (size_t)rowK * 3072 + (((lane & 15) ^ (rowK & 7)) << 3);
        int rowV = w * 32 + i * 8 + (lane >> 3);
        gV[i] = Vbase + (size_t)rowV * 2048 + (((lane & 7) ^ (rowV & 7)) << 3);
    }

    const int swz = (q & 7) << 3;
    int tcK[4];
    #pragma unroll
    for (int t = 0; t < 4; ++t) tcK[t] = (t * 32 + g * 8) ^ swz;

    unsigned short* Pw = Plds[w];

    float m_run[2] = {-INFINITY, -INFINITY};
    float l_run[2] = {0.f, 0.f};
    f32x4 o[2][8];
    #pragma unroll
    for (int u = 0; u < 2; ++u)
        #pragma unroll
        for (int nf = 0; nf < 8; ++nf) o[u][nf] = (f32x4){0.f, 0.f, 0.f, 0.f};

    auto STAGE = [&](int buf) {
        #pragma unroll
        for (int i = 0; i < 4; ++i) {
            gload16(gK[i], &Ks[buf][w * 2048 + i * 512]);
            gload16(gV[i], &Vs[buf][w * 2048 + i * 512]);
            gK[i] += 64 * 3072;
            gV[i] += 64;
        }
    };

    STAGE(0);
    int cur = 0;
    for (int t0 = 0; t0 < 32; ++t0) {
        if (t0 > 0) __builtin_amdgcn_s_barrier();
        if (t0 + 1 < 32) {
            STAGE(cur ^ 1);
            asm volatile("s_waitcnt vmcnt(8)" ::: "memory");
        } else {
            asm volatile("s_waitcnt vmcnt(0)" ::: "memory");
        }
        __builtin_amdgcn_s_barrier();

        const unsigned short* Kt = Ks[cur];
        const unsigned short* Vt = Vs[cur];

        f32x4 st[2][4];
        #pragma unroll
        for (int ks = 0; ks < 4; ++ks) {
            f32x4 a0 = (f32x4){0.f, 0.f, 0.f, 0.f};
            f32x4 a1 = (f32x4){0.f, 0.f, 0.f, 0.f};
            int rb = (ks * 16 + q) * 128;
            #pragma unroll
            for (int t = 0; t < 4; ++t) {
                short8 kf = *(const short8*)&Kt[rb + tcK[t]];
                a0 = __builtin_amdgcn_mfma_f32_16x16x32_bf16(kf, qf[0][t], a0, 0, 0, 0);
                a1 = __builtin_amdgcn_mfma_f32_16x16x32_bf16(kf, qf[1][t], a1, 0, 0, 0);
            }
            st[0][ks] = a0; st[1][ks] = a1;
        }

        short8 vf[8][2];
        #pragma unroll
        for (int nf = 0; nf < 8; ++nf) {
            int rb = (nf * 16 + q) * 64;
            #pragma unroll
            for (int t = 0; t < 2; ++t) vf[nf][t] = *(const short8*)&Vt[rb + tcK[t]];
        }

        #pragma unroll
        for (int u = 0; u < 2; ++u) {
            float mx = fmaxf(
                fmaxf(fmaxf(fmaxf(st[u][0][0], st[u][0][1]), fmaxf(st[u][0][2], st[u][0][3])),
                      fmaxf(fmaxf(st[u][1][0], st[u][1][1]), fmaxf(st[u][1][2], st[u][1][3]))),
                fmaxf(fmaxf(fmaxf(st[u][2][0], st[u][2][1]), fmaxf(st[u][2][2], st[u][2][3])),
                      fmaxf(fmaxf(st[u][3][0], st[u][3][1]), fmaxf(st[u][3][2], st[u][3][3]))));
            mx = fmaxf(mx, __shfl_xor(mx, 16));
            mx = fmaxf(mx, __shfl_xor(mx, 32));
            if (__any(mx - m_run[u] > 8.0f)) {          // defer-max (exp2 domain)
                float mn = fmaxf(m_run[u], mx);
                float sc = exp2_fast(m_run[u] - mn);
                l_run[u] *= sc;
                f32x4 sv;
                #pragma unroll
                for (int rr = 0; rr < 4; ++rr) sv[rr] = __shfl(sc, 4 * g + rr);
                #pragma unroll
                for (int nf = 0; nf < 8; ++nf) o[u][nf] *= sv;
                m_run[u] = mn;
            }
            f32x4 pe[4];
            #pragma unroll
            for (int ks = 0; ks < 4; ++ks)
                #pragma unroll
                for (int rr = 0; rr < 4; ++rr) pe[ks][rr] = exp2_fast(st[u][ks][rr] - m_run[u]);
            f32x4 ls4 = (pe[0] + pe[1]) + (pe[2] + pe[3]);
            float ls = (ls4[0] + ls4[1]) + (ls4[2] + ls4[3]);
            ls += __shfl_xor(ls, 16);
            ls += __shfl_xor(ls, 32);
            l_run[u] += ls;

            #pragma unroll
            for (int ks = 0; ks < 4; ++ks) {
                u16x4 pk;
                #pragma unroll
                for (int rr = 0; rr < 4; ++rr) pk[rr] = f2bf(pe[ks][rr]);
                *(u16x4*)&Pw[q * 72 + ks * 16 + 4 * g] = pk;
            }
            asm volatile("s_waitcnt lgkmcnt(0)" ::: "memory");
            short8 pa0 = *(const short8*)&Pw[q * 72 + g * 8];
            short8 pa1 = *(const short8*)&Pw[q * 72 + 32 + g * 8];

            #pragma unroll
            for (int nf = 0; nf < 8; ++nf) {
                f32x4 a = o[u][nf];
                a = __builtin_amdgcn_mfma_f32_16x16x32_bf16(pa0, vf[nf][0], a, 0, 0, 0);
                a = __builtin_amdgcn_mfma_f32_16x16x32_bf16(pa1, vf[nf][1], a, 0, 0, 0);
                o[u][nf] = a;
            }
        }
        cur ^= 1;
    }

    #pragma unroll
    for (int u = 0; u < 2; ++u) {
        f32x4 li;
        #pragma unroll
        for (int rr = 0; rr < 4; ++rr) li[rr] = __shfl(l_run[u], 4 * g + rr);
        #pragma unroll
        for (int nf = 0; nf < 8; ++nf)
            #pragma unroll
            for (int rr = 0; rr < 4; ++rr) {
                size_t row = (size_t)(b * 2048 + qrow + u * 16 + 4 * g + rr);
                aout[row * 2048 + h * 128 + nf * 16 + q] = f2bf(o[u][nf][rr] / li[rr]);
            }
    }
}

extern "C" void kernel_launch(void* const* d_in, const int* in_sizes, int n_in,
                              void* d_out, int out_size, void* d_ws, size_t ws_size,
                              hipStream_t stream) {
    (void)in_sizes; (void)n_in; (void)out_size; (void)ws_size;
    const float* hs = (const float*)d_in[0];
    const int* pos  = (const int*)d_in[1];
    const float* wq = (const float*)d_in[2];
    const float* wk = (const float*)d_in[3];
    const float* wv = (const float*)d_in[4];
    const float* wo = (const float*)d_in[5];
    float* out = (float*)d_out;

    unsigned short* hsb   = (unsigned short*)d_ws;              // 4096*2048
    unsigned short* wqkvb = hsb + (size_t)4096 * 2048;          // 3072*2048
    unsigned short* wob   = wqkvb + (size_t)3072 * 2048;        // 2048*2048
    unsigned short* qkvt  = wob + (size_t)2048 * 2048;          // 4096*3072 (q|k used)
    unsigned short* vtb   = qkvt + (size_t)4096 * 3072;         // 8*128*2048
    float2* tb            = (float2*)(vtb + (size_t)8 * 128 * 2048);   // 4096*64
    unsigned short* aoutb = (unsigned short*)(tb + (size_t)4096 * 64); // 4096*2048

    k_prep<<<19456, 256, 0, stream>>>(hs, wq, wk, wv, wo, pos, hsb, wqkvb, wob, tb);
    k_gemm8<1><<<dim3(12, 16), 512, 0, stream>>>(hsb, wqkvb, nullptr, qkvt, vtb, tb, 4096, 3072, 2048);
    k_flash<<<dim3(512), 256, 0, stream>>>(qkvt, vtb, aoutb);
    k_gemm8<0><<<dim3(16, 16), 512, 0, stream>>>(aoutb, wob, out, nullptr, nullptr, nullptr, 4096, 2048, 2048);
}

// Round 8
// 255.729 us; speedup vs baseline: 1.0429x; 1.0429x over previous
//
#include <hip/hip_runtime.h>
#include <hip/hip_bf16.h>
#include <math.h>

// B=2, S=2048, D=2048, H=16, KV=4, HD=128, n_rep=4
// qkv layout per row (b*2048+s): [0,2048) q | [2048,2560) k  (v goes straight to vt)
// wqkv is column-PERMUTED for q/k heads: head-local col c holds orig d = (c>>1)+((c&1)<<6)
// Q is scaled by (1/sqrt(128))*log2(e): flash softmax runs in exp2 domain.

typedef __attribute__((ext_vector_type(4))) float f32x4;
typedef __attribute__((ext_vector_type(8))) short short8;
typedef __attribute__((ext_vector_type(4))) unsigned short u16x4;
typedef __attribute__((ext_vector_type(8))) unsigned short u16x8;

static __device__ __forceinline__ unsigned short f2bf(float x) {
    unsigned u = __builtin_bit_cast(unsigned, x);
    u += 0x7fffu + ((u >> 16) & 1u);          // RNE
    return (unsigned short)(u >> 16);
}
static __device__ __forceinline__ float exp2_fast(float x) {
    float r;
    asm volatile("v_exp_f32 %0, %1" : "=v"(r) : "v"(x));
    return r;
}
static __device__ __forceinline__ void gload16(const unsigned short* g, unsigned short* lds) {
    __builtin_amdgcn_global_load_lds((const __attribute__((address_space(1))) void*)g,
                                     (__attribute__((address_space(3))) void*)lds, 16, 0, 0);
}

// ---------------- fused prep: hs->bf16 | wqkv permuted concat | wo->bf16 | rope table ----
__global__ __launch_bounds__(256) void k_prep(const float* __restrict__ hs,
                                              const float* __restrict__ wq,
                                              const float* __restrict__ wk,
                                              const float* __restrict__ wv,
                                              const float* __restrict__ wo,
                                              const int* __restrict__ pos_ids,
                                              unsigned short* __restrict__ hsb,
                                              unsigned short* __restrict__ wqkvb,
                                              unsigned short* __restrict__ wob,
                                              float2* __restrict__ tb) {
    long idx = (long)blockIdx.x * 256 + threadIdx.x;
    if (idx < 2097152) {                       // hs -> bf16
        f32x4 v = ((const f32x4*)hs)[idx];
        u16x4 o;
        o.x = f2bf(v.x); o.y = f2bf(v.y); o.z = f2bf(v.z); o.w = f2bf(v.w);
        ((u16x4*)hsb)[idx] = o;
    } else if (idx < 3670016) {                // wqkv concat (q/k col-permuted)
        long i = idx - 2097152;
        long flat = i * 4;
        int row = (int)(flat >> 11);
        int col = (int)(flat & 2047);
        const float* src;
        if (row < 2560) {
            int base = row & 2047;
            int hh = base >> 7, ii = base & 127;
            int d = (ii >> 1) + ((ii & 1) << 6);
            src = (row < 2048 ? wq : wk) + (size_t)(hh * 128 + d) * 2048;
        } else {
            src = wv + (size_t)(row - 2560) * 2048;
        }
        f32x4 v = *(const f32x4*)(src + col);
        u16x4 o;
        o.x = f2bf(v.x); o.y = f2bf(v.y); o.z = f2bf(v.z); o.w = f2bf(v.w);
        *(u16x4*)(wqkvb + flat) = o;
    } else if (idx < 4718592) {                // wo -> bf16
        long i = idx - 3670016;
        f32x4 v = ((const f32x4*)wo)[i];
        u16x4 o;
        o.x = f2bf(v.x); o.y = f2bf(v.y); o.z = f2bf(v.z); o.w = f2bf(v.w);
        ((u16x4*)wob)[i] = o;
    } else {                                   // rope table
        long j = idx - 4718592;                // [0, 262144)
        int r = (int)(j >> 6);
        int i = (int)(j & 63);
        float pos = (float)pos_ids[r];
        float powv = (float)pow(10000.0, (double)i / 64.0);
        float invf = 1.0f / powv;
        float arg  = pos * invf;
        double a = (double)arg;
        tb[(size_t)r * 64 + i] = make_float2((float)cos(a), (float)sin(a));
    }
}

// ---------------- GEMM (R6 known-good): C[M][N] = A[M][K] * W[N][K]^T ----------------
// 128x128 tile, BK=32, 4 waves (2x2), dbuf LDS + global_load_lds w16 + counted vmcnt.
// XCD-aware bijective block swizzle.
// EPI 0: f32 store (O-proj). EPI 1: fused QKV epilogue (RoPE q/k, V transposed to vt).
template <int EPI>
__global__ __launch_bounds__(256) void k_gemm(const unsigned short* __restrict__ A,
                                              const unsigned short* __restrict__ W,
                                              float* __restrict__ Cf,
                                              unsigned short* __restrict__ qkvt,
                                              unsigned short* __restrict__ vtb,
                                              const float2* __restrict__ tb,
                                              int M, int N, int K) {
    __shared__ unsigned short As[2][4096];   // 128 rows x 32 shorts
    __shared__ unsigned short Ws[2][4096];
    const int tid = threadIdx.x;
    const int lane = tid & 63;
    const int w = tid >> 6;
    const int q = lane & 15, g = lane >> 4;
    const int wr = w >> 1, wc = w & 1;

    // XCD swizzle (bijective: gridDim.x*gridDim.y % 8 == 0)
    const int nwg = gridDim.x * gridDim.y;
    const int id = blockIdx.y * gridDim.x + blockIdx.x;
    const int swz_id = (id & 7) * (nwg >> 3) + (id >> 3);
    const int bx = swz_id % gridDim.x;
    const int by = swz_id / gridDim.x;
    const long mbase = (long)by * 128;
    const long nbase = (long)bx * 128;

    const unsigned short* gA[2];
    const unsigned short* gW[2];
    #pragma unroll
    for (int j = 0; j < 2; ++j) {
        int r = j * 64 + (tid >> 2);
        int slot = (tid & 3) ^ ((r >> 1) & 3);
        gA[j] = A + (size_t)(mbase + r) * K + slot * 8;
        gW[j] = W + (size_t)(nbase + r) * K + slot * 8;
    }
    const int sa = (g ^ ((q >> 1) & 3)) * 8;   // read slot offset (shorts)

    f32x4 acc[4][4];
    #pragma unroll
    for (int m = 0; m < 4; ++m)
        #pragma unroll
        for (int n = 0; n < 4; ++n) acc[m][n] = (f32x4){0.f, 0.f, 0.f, 0.f};

    auto STAGE = [&](int buf) {
        #pragma unroll
        for (int j = 0; j < 2; ++j) {
            gload16(gA[j], &As[buf][j * 2048 + w * 512]);
            gload16(gW[j], &Ws[buf][j * 2048 + w * 512]);
            gA[j] += 32; gW[j] += 32;
        }
    };

    const int nk = K >> 5;
    STAGE(0);
    int cur = 0;
    for (int t = 0; t < nk; ++t) {
        if (t) __builtin_amdgcn_s_barrier();            // prev buffer free
        if (t + 1 < nk) {
            STAGE(cur ^ 1);
            asm volatile("s_waitcnt vmcnt(4)" ::: "memory");   // this tile's loads done
        } else {
            asm volatile("s_waitcnt vmcnt(0)" ::: "memory");
        }
        __builtin_amdgcn_s_barrier();                   // tile visible to all waves

        short8 af[4], bfr[4];
        #pragma unroll
        for (int m = 0; m < 4; ++m) af[m] = *(const short8*)&As[cur][(wr * 64 + m * 16 + q) * 32 + sa];
        #pragma unroll
        for (int n = 0; n < 4; ++n) bfr[n] = *(const short8*)&Ws[cur][(wc * 64 + n * 16 + q) * 32 + sa];
        #pragma unroll
        for (int m = 0; m < 4; ++m)
            #pragma unroll
            for (int n = 0; n < 4; ++n)
                acc[m][n] = __builtin_amdgcn_mfma_f32_16x16x32_bf16(af[m], bfr[n], acc[m][n], 0, 0, 0);
        cur ^= 1;
    }

    if (EPI == 0) {
        #pragma unroll
        for (int m = 0; m < 4; ++m)
            #pragma unroll
            for (int n = 0; n < 4; ++n)
                #pragma unroll
                for (int rr = 0; rr < 4; ++rr) {
                    long row = mbase + wr * 64 + m * 16 + 4 * g + rr;
                    long col = nbase + wc * 64 + n * 16 + q;
                    Cf[row * N + col] = acc[m][n][rr];
                }
    } else {
        const int tile = bx;
        if (tile >= 20) {
            // V tile -> vt[(b*4+kv)*128+c][s], 4 consecutive s per store
            const int kv = tile - 20;
            #pragma unroll
            for (int m = 0; m < 4; ++m)
                #pragma unroll
                for (int n = 0; n < 4; ++n) {
                    int c = wc * 64 + n * 16 + q;
                    long r0 = mbase + wr * 64 + m * 16 + 4 * g;
                    int b = (int)(r0 >> 11), s0 = (int)(r0 & 2047);
                    u16x4 pk;
                    #pragma unroll
                    for (int rr = 0; rr < 4; ++rr) pk[rr] = f2bf(acc[m][n][rr]);
                    *(u16x4*)(vtb + (size_t)((b * 4 + kv) * 128 + c) * 2048 + s0) = pk;
                }
        } else {
            // q/k tile: RoPE from permuted cols; un-permute on store
            const float scale = (tile < 16) ? 0.12751744f : 1.0f;  // (1/sqrt(128))*log2e for q
            const float sgn = (q & 1) ? 1.f : -1.f;
            #pragma unroll
            for (int m = 0; m < 4; ++m)
                #pragma unroll
                for (int rr = 0; rr < 4; ++rr) {
                    long row = mbase + wr * 64 + m * 16 + 4 * g + rr;
                    #pragma unroll
                    for (int n = 0; n < 4; ++n) {
                        int c = wc * 64 + n * 16 + q;
                        float x = acc[m][n][rr];
                        float p = __shfl_xor(x, 1);
                        float2 cs = tb[row * 64 + (c >> 1)];
                        float y = (x * cs.x + sgn * (p * cs.y)) * scale;
                        int dorig = (c >> 1) + ((c & 1) << 6);
                        long col = (tile < 16) ? (tile * 128 + dorig)
                                               : (2048 + (tile - 16) * 128 + dorig);
                        qkvt[row * 3072 + col] = f2bf(y);
                    }
                }
        }
    }
}

// ---------------- Flash attention v8: occupancy-focused ----------------
// 1024 blocks (one (b,kvh) per XCD), 4 waves x 16 queries, KVBLK=32.
// K [32x128] + V^T [128x32] double-buffered via global_load_lds (XOR-swizzled source),
// counted vmcnt(4). LDS 37.9KB -> up to 4 blocks/CU. exp2-domain defer-max softmax.
__global__ __launch_bounds__(256, 3) void k_flash(const unsigned short* __restrict__ qkv,
                                                  const unsigned short* __restrict__ vt,
                                                  unsigned short* __restrict__ aout) {
    __shared__ unsigned short Ks[2][4096];   // 32 keys x 128 hd, dbuf
    __shared__ unsigned short Vs[2][4096];   // 128 d x 32 keys, dbuf
    __shared__ unsigned short Plds[4][640];  // per-wave 16 x 40
    const int wg = blockIdx.x;
    const int kvg = wg & 7;            // b*4+kvh -> pinned per XCD
    const int inner = wg >> 3;         // 0..127
    const int h_in = inner & 3;
    const int qt = inner >> 2;         // 0..31
    const int b = kvg >> 2, kvh = kvg & 3;
    const int h = kvh * 4 + h_in;
    const int tid = threadIdx.x;
    const int w = tid >> 6, lane = tid & 63;
    const int q = lane & 15, g = lane >> 4;
    const int qrow = qt * 64 + w * 16;

    // Q fragments (B-operand of swapped QK^T): row=q, k=8g+i (+32t)
    short8 qf[4];
    {
        const unsigned short* Qp = qkv + (size_t)(b * 2048 + qrow + q) * 3072 + h * 128 + g * 8;
        #pragma unroll
        for (int t = 0; t < 4; ++t) qf[t] = *(const short8*)(Qp + t * 32);
    }

    const unsigned short* Kbase = qkv + (size_t)(b * 2048) * 3072 + 2048 + kvh * 128;
    const unsigned short* Vbase = vt + (size_t)((b * 4 + kvh) * 128) * 2048;
    const unsigned short* gK[2];
    const unsigned short* gV[2];
    #pragma unroll
    for (int j = 0; j < 2; ++j) {
        int rK = j * 16 + (tid >> 4);                  // 0..31 (local key row)
        gK[j] = Kbase + (size_t)rK * 3072 + (((tid & 15) ^ (rK & 7)) << 3);
        int rV = j * 64 + (tid >> 2);                  // 0..127 (d row)
        gV[j] = Vbase + (size_t)rV * 2048 + (((tid & 3) ^ (rV & 3)) << 3);
    }

    const int swz = (q & 7) << 3;
    int tcK[4];
    #pragma unroll
    for (int t = 0; t < 4; ++t) tcK[t] = (t * 32 + g * 8) ^ swz;
    const int tcV = (g ^ (q & 3)) * 8;

    unsigned short* Pw = Plds[w];

    float m_run = -INFINITY, l_run = 0.f;
    f32x4 o[8];
    #pragma unroll
    for (int nf = 0; nf < 8; ++nf) o[nf] = (f32x4){0.f, 0.f, 0.f, 0.f};

    auto STAGE = [&](int buf) {
        #pragma unroll
        for (int j = 0; j < 2; ++j) {
            gload16(gK[j], &Ks[buf][j * 2048 + w * 512]);
            gload16(gV[j], &Vs[buf][j * 2048 + w * 512]);
            gK[j] += 32 * 3072;
            gV[j] += 32;
        }
    };

    STAGE(0);
    int cur = 0;
    for (int t0 = 0; t0 < 64; ++t0) {
        if (t0 > 0) __builtin_amdgcn_s_barrier();
        if (t0 + 1 < 64) {
            STAGE(cur ^ 1);
            asm volatile("s_waitcnt vmcnt(4)" ::: "memory");
        } else {
            asm volatile("s_waitcnt vmcnt(0)" ::: "memory");
        }
        __builtin_amdgcn_s_barrier();

        const unsigned short* Kt = Ks[cur];
        const unsigned short* Vt = Vs[cur];

        // ---- QK^T (swapped): st[ks] = S^T[key=ks*16+4g+rr][query q] ----
        f32x4 st[2];
        #pragma unroll
        for (int ks = 0; ks < 2; ++ks) {
            f32x4 a = (f32x4){0.f, 0.f, 0.f, 0.f};
            int rb = (ks * 16 + q) * 128;
            #pragma unroll
            for (int t = 0; t < 4; ++t) {
                short8 kf = *(const short8*)&Kt[rb + tcK[t]];
                a = __builtin_amdgcn_mfma_f32_16x16x32_bf16(kf, qf[t], a, 0, 0, 0);
            }
            st[ks] = a;
        }

        // ---- V fragments to registers (overlaps softmax VALU) ----
        short8 vf[8];
        #pragma unroll
        for (int nf = 0; nf < 8; ++nf)
            vf[nf] = *(const short8*)&Vt[(nf * 16 + q) * 32 + tcV];

        // ---- online softmax (exp2 domain, defer-max) ----
        float mx = fmaxf(fmaxf(fmaxf(st[0][0], st[0][1]), fmaxf(st[0][2], st[0][3])),
                         fmaxf(fmaxf(st[1][0], st[1][1]), fmaxf(st[1][2], st[1][3])));
        mx = fmaxf(mx, __shfl_xor(mx, 16));
        mx = fmaxf(mx, __shfl_xor(mx, 32));
        if (__any(mx - m_run > 8.0f)) {
            float mn = fmaxf(m_run, mx);
            float sc = exp2_fast(m_run - mn);
            l_run *= sc;
            f32x4 sv;
            #pragma unroll
            for (int rr = 0; rr < 4; ++rr) sv[rr] = __shfl(sc, 4 * g + rr);
            #pragma unroll
            for (int nf = 0; nf < 8; ++nf) o[nf] *= sv;
            m_run = mn;
        }
        f32x4 pe[2];
        #pragma unroll
        for (int ks = 0; ks < 2; ++ks)
            #pragma unroll
            for (int rr = 0; rr < 4; ++rr) pe[ks][rr] = exp2_fast(st[ks][rr] - m_run);
        f32x4 ls4 = pe[0] + pe[1];
        float ls = (ls4[0] + ls4[1]) + (ls4[2] + ls4[3]);
        ls += __shfl_xor(ls, 16);
        ls += __shfl_xor(ls, 32);
        l_run += ls;

        // ---- P -> bf16 via per-wave LDS (transpose S^T -> P[q][key]) ----
        #pragma unroll
        for (int ks = 0; ks < 2; ++ks) {
            u16x4 pk;
            #pragma unroll
            for (int rr = 0; rr < 4; ++rr) pk[rr] = f2bf(pe[ks][rr]);
            *(u16x4*)&Pw[q * 40 + ks * 16 + 4 * g] = pk;
        }
        asm volatile("s_waitcnt lgkmcnt(0)" ::: "memory");
        short8 pa = *(const short8*)&Pw[q * 40 + g * 8];

        // ---- PV ----
        #pragma unroll
        for (int nf = 0; nf < 8; ++nf)
            o[nf] = __builtin_amdgcn_mfma_f32_16x16x32_bf16(pa, vf[nf], o[nf], 0, 0, 0);

        cur ^= 1;
    }

    // normalize and store: aout[b*2048 + qrow + 4g+rr][h*128 + nf*16 + q]
    f32x4 li;
    #pragma unroll
    for (int rr = 0; rr < 4; ++rr) li[rr] = __shfl(l_run, 4 * g + rr);
    #pragma unroll
    for (int rr = 0; rr < 4; ++rr) li[rr] = 1.0f / li[rr];
    #pragma unroll
    for (int nf = 0; nf < 8; ++nf)
        #pragma unroll
        for (int rr = 0; rr < 4; ++rr) {
            size_t row = (size_t)(b * 2048 + qrow + 4 * g + rr);
            aout[row * 2048 + h * 128 + nf * 16 + q] = f2bf(o[nf][rr] * li[rr]);
        }
}

extern "C" void kernel_launch(void* const* d_in, const int* in_sizes, int n_in,
                              void* d_out, int out_size, void* d_ws, size_t ws_size,
                              hipStream_t stream) {
    (void)in_sizes; (void)n_in; (void)out_size; (void)ws_size;
    const float* hs = (const float*)d_in[0];
    const int* pos  = (const int*)d_in[1];
    const float* wq = (const float*)d_in[2];
    const float* wk = (const float*)d_in[3];
    const float* wv = (const float*)d_in[4];
    const float* wo = (const float*)d_in[5];
    float* out = (float*)d_out;

    unsigned short* hsb   = (unsigned short*)d_ws;              // 4096*2048
    unsigned short* wqkvb = hsb + (size_t)4096 * 2048;          // 3072*2048
    unsigned short* wob   = wqkvb + (size_t)3072 * 2048;        // 2048*2048
    unsigned short* qkvt  = wob + (size_t)2048 * 2048;          // 4096*3072 (q|k used)
    unsigned short* vtb   = qkvt + (size_t)4096 * 3072;         // 8*128*2048
    float2* tb            = (float2*)(vtb + (size_t)8 * 128 * 2048);   // 4096*64
    unsigned short* aoutb = (unsigned short*)(tb + (size_t)4096 * 64); // 4096*2048

    k_prep<<<19456, 256, 0, stream>>>(hs, wq, wk, wv, wo, pos, hsb, wqkvb, wob, tb);
    k_gemm<1><<<dim3(24, 32), 256, 0, stream>>>(hsb, wqkvb, nullptr, qkvt, vtb, tb, 4096, 3072, 2048);
    k_flash<<<dim3(1024), 256, 0, stream>>>(qkvt, vtb, aoutb);
    k_gemm<0><<<dim3(16, 32), 256, 0, stream>>>(aoutb, wob, out, nullptr, nullptr, nullptr, 4096, 2048, 2048);
}

// Round 9
// 220.902 us; speedup vs baseline: 1.2073x; 1.1577x over previous
//
#include <hip/hip_runtime.h>
#include <hip/hip_bf16.h>
#include <math.h>

// B=2, S=2048, D=2048, H=16, KV=4, HD=128, n_rep=4
// qkv layout per row (b*2048+s): [0,2048) q | [2048,2560) k  (v goes straight to vt)
// wqkv is column-PERMUTED for q/k heads: head-local col c holds orig d = (c>>1)+((c&1)<<6)
// Q is scaled by (1/sqrt(128))*log2(e): flash softmax runs in exp2 domain.

typedef __attribute__((ext_vector_type(4))) float f32x4;
typedef __attribute__((ext_vector_type(8))) short short8;
typedef __attribute__((ext_vector_type(4))) unsigned short u16x4;
typedef __attribute__((ext_vector_type(8))) unsigned short u16x8;

static __device__ __forceinline__ unsigned short f2bf(float x) {
    unsigned u = __builtin_bit_cast(unsigned, x);
    u += 0x7fffu + ((u >> 16) & 1u);          // RNE
    return (unsigned short)(u >> 16);
}
static __device__ __forceinline__ float exp2_fast(float x) {
    float r;
    asm volatile("v_exp_f32 %0, %1" : "=v"(r) : "v"(x));
    return r;
}
static __device__ __forceinline__ unsigned cvt_pk_bf16(float a, float b) {
    unsigned r;                                // low16 = bf16(a), high16 = bf16(b)
    asm("v_cvt_pk_bf16_f32 %0, %1, %2" : "=v"(r) : "v"(a), "v"(b));
    return r;
}
static __device__ __forceinline__ void gload16(const unsigned short* g, unsigned short* lds) {
    __builtin_amdgcn_global_load_lds((const __attribute__((address_space(1))) void*)g,
                                     (__attribute__((address_space(3))) void*)lds, 16, 0, 0);
}

// ---------------- fused prep: hs->bf16 | wqkv permuted concat | wo->bf16 | rope table ----
__global__ __launch_bounds__(256) void k_prep(const float* __restrict__ hs,
                                              const float* __restrict__ wq,
                                              const float* __restrict__ wk,
                                              const float* __restrict__ wv,
                                              const float* __restrict__ wo,
                                              const int* __restrict__ pos_ids,
                                              unsigned short* __restrict__ hsb,
                                              unsigned short* __restrict__ wqkvb,
                                              unsigned short* __restrict__ wob,
                                              float2* __restrict__ tb) {
    long idx = (long)blockIdx.x * 256 + threadIdx.x;
    if (idx < 2097152) {                       // hs -> bf16
        f32x4 v = ((const f32x4*)hs)[idx];
        u16x4 o;
        o.x = f2bf(v.x); o.y = f2bf(v.y); o.z = f2bf(v.z); o.w = f2bf(v.w);
        ((u16x4*)hsb)[idx] = o;
    } else if (idx < 3670016) {                // wqkv concat (q/k col-permuted)
        long i = idx - 2097152;
        long flat = i * 4;
        int row = (int)(flat >> 11);
        int col = (int)(flat & 2047);
        const float* src;
        if (row < 2560) {
            int base = row & 2047;
            int hh = base >> 7, ii = base & 127;
            int d = (ii >> 1) + ((ii & 1) << 6);
            src = (row < 2048 ? wq : wk) + (size_t)(hh * 128 + d) * 2048;
        } else {
            src = wv + (size_t)(row - 2560) * 2048;
        }
        f32x4 v = *(const f32x4*)(src + col);
        u16x4 o;
        o.x = f2bf(v.x); o.y = f2bf(v.y); o.z = f2bf(v.z); o.w = f2bf(v.w);
        *(u16x4*)(wqkvb + flat) = o;
    } else if (idx < 4718592) {                // wo -> bf16
        long i = idx - 3670016;
        f32x4 v = ((const f32x4*)wo)[i];
        u16x4 o;
        o.x = f2bf(v.x); o.y = f2bf(v.y); o.z = f2bf(v.z); o.w = f2bf(v.w);
        ((u16x4*)wob)[i] = o;
    } else {                                   // rope table (f32 fast path)
        long j = idx - 4718592;                // [0, 262144)
        int r = (int)(j >> 6);
        int i = (int)(j & 63);
        float pos = (float)pos_ids[r];
        float invf = exp2f((float)i * -0.20762050593046f);  // 10000^(-i/64)
        float arg  = pos * invf;
        float s, c;
        sincosf(arg, &s, &c);                  // accurate f32 sincos
        tb[(size_t)r * 64 + i] = make_float2(c, s);
    }
}

// ---------------- GEMM (R6 known-good): C[M][N] = A[M][K] * W[N][K]^T ----------------
// 128x128 tile, BK=32, 4 waves (2x2), dbuf LDS + global_load_lds w16 + counted vmcnt.
// XCD-aware bijective block swizzle.
// EPI 0: f32 store (O-proj). EPI 1: fused QKV epilogue (RoPE q/k, V transposed to vt).
template <int EPI>
__global__ __launch_bounds__(256) void k_gemm(const unsigned short* __restrict__ A,
                                              const unsigned short* __restrict__ W,
                                              float* __restrict__ Cf,
                                              unsigned short* __restrict__ qkvt,
                                              unsigned short* __restrict__ vtb,
                                              const float2* __restrict__ tb,
                                              int M, int N, int K) {
    __shared__ unsigned short As[2][4096];   // 128 rows x 32 shorts
    __shared__ unsigned short Ws[2][4096];
    const int tid = threadIdx.x;
    const int lane = tid & 63;
    const int w = tid >> 6;
    const int q = lane & 15, g = lane >> 4;
    const int wr = w >> 1, wc = w & 1;

    // XCD swizzle (bijective: gridDim.x*gridDim.y % 8 == 0)
    const int nwg = gridDim.x * gridDim.y;
    const int id = blockIdx.y * gridDim.x + blockIdx.x;
    const int swz_id = (id & 7) * (nwg >> 3) + (id >> 3);
    const int bx = swz_id % gridDim.x;
    const int by = swz_id / gridDim.x;
    const long mbase = (long)by * 128;
    const long nbase = (long)bx * 128;

    const unsigned short* gA[2];
    const unsigned short* gW[2];
    #pragma unroll
    for (int j = 0; j < 2; ++j) {
        int r = j * 64 + (tid >> 2);
        int slot = (tid & 3) ^ ((r >> 1) & 3);
        gA[j] = A + (size_t)(mbase + r) * K + slot * 8;
        gW[j] = W + (size_t)(nbase + r) * K + slot * 8;
    }
    const int sa = (g ^ ((q >> 1) & 3)) * 8;   // read slot offset (shorts)

    f32x4 acc[4][4];
    #pragma unroll
    for (int m = 0; m < 4; ++m)
        #pragma unroll
        for (int n = 0; n < 4; ++n) acc[m][n] = (f32x4){0.f, 0.f, 0.f, 0.f};

    auto STAGE = [&](int buf) {
        #pragma unroll
        for (int j = 0; j < 2; ++j) {
            gload16(gA[j], &As[buf][j * 2048 + w * 512]);
            gload16(gW[j], &Ws[buf][j * 2048 + w * 512]);
            gA[j] += 32; gW[j] += 32;
        }
    };

    const int nk = K >> 5;
    STAGE(0);
    int cur = 0;
    for (int t = 0; t < nk; ++t) {
        if (t) __builtin_amdgcn_s_barrier();            // prev buffer free
        if (t + 1 < nk) {
            STAGE(cur ^ 1);
            asm volatile("s_waitcnt vmcnt(4)" ::: "memory");   // this tile's loads done
        } else {
            asm volatile("s_waitcnt vmcnt(0)" ::: "memory");
        }
        __builtin_amdgcn_s_barrier();                   // tile visible to all waves

        short8 af[4], bfr[4];
        #pragma unroll
        for (int m = 0; m < 4; ++m) af[m] = *(const short8*)&As[cur][(wr * 64 + m * 16 + q) * 32 + sa];
        #pragma unroll
        for (int n = 0; n < 4; ++n) bfr[n] = *(const short8*)&Ws[cur][(wc * 64 + n * 16 + q) * 32 + sa];
        #pragma unroll
        for (int m = 0; m < 4; ++m)
            #pragma unroll
            for (int n = 0; n < 4; ++n)
                acc[m][n] = __builtin_amdgcn_mfma_f32_16x16x32_bf16(af[m], bfr[n], acc[m][n], 0, 0, 0);
        cur ^= 1;
    }

    if (EPI == 0) {
        #pragma unroll
        for (int m = 0; m < 4; ++m)
            #pragma unroll
            for (int n = 0; n < 4; ++n)
                #pragma unroll
                for (int rr = 0; rr < 4; ++rr) {
                    long row = mbase + wr * 64 + m * 16 + 4 * g + rr;
                    long col = nbase + wc * 64 + n * 16 + q;
                    Cf[row * N + col] = acc[m][n][rr];
                }
    } else {
        const int tile = bx;
        if (tile >= 20) {
            // V tile -> vt[(b*4+kv)*128+c][s], 4 consecutive s per store
            const int kv = tile - 20;
            #pragma unroll
            for (int m = 0; m < 4; ++m)
                #pragma unroll
                for (int n = 0; n < 4; ++n) {
                    int c = wc * 64 + n * 16 + q;
                    long r0 = mbase + wr * 64 + m * 16 + 4 * g;
                    int b = (int)(r0 >> 11), s0 = (int)(r0 & 2047);
                    uint2 pk;
                    pk.x = cvt_pk_bf16(acc[m][n][0], acc[m][n][1]);
                    pk.y = cvt_pk_bf16(acc[m][n][2], acc[m][n][3]);
                    *(uint2*)(vtb + (size_t)((b * 4 + kv) * 128 + c) * 2048 + s0) = pk;
                }
        } else {
            // q/k tile: RoPE from permuted cols; un-permute on store
            const float scale = (tile < 16) ? 0.12751744f : 1.0f;  // (1/sqrt(128))*log2e for q
            const float sgn = (q & 1) ? 1.f : -1.f;
            #pragma unroll
            for (int m = 0; m < 4; ++m)
                #pragma unroll
                for (int rr = 0; rr < 4; ++rr) {
                    long row = mbase + wr * 64 + m * 16 + 4 * g + rr;
                    #pragma unroll
                    for (int n = 0; n < 4; ++n) {
                        int c = wc * 64 + n * 16 + q;
                        float x = acc[m][n][rr];
                        float p = __shfl_xor(x, 1);
                        float2 cs = tb[row * 64 + (c >> 1)];
                        float y = (x * cs.x + sgn * (p * cs.y)) * scale;
                        int dorig = (c >> 1) + ((c & 1) << 6);
                        long col = (tile < 16) ? (tile * 128 + dorig)
                                               : (2048 + (tile - 16) * 128 + dorig);
                        qkvt[row * 3072 + col] = f2bf(y);
                    }
                }
        }
    }
}

// ---------------- Flash attention (R6 known-good + cvt_pk P-pack + rcp normalize) ----
// 512 blocks (one (b,kvh) per XCD), 4 waves x 32 queries, KVBLK=64, exp2-domain softmax.
// K and V LDS-staged (dbuf, gload_lds, XOR-swizzle), counted vmcnt(8).
__global__ __launch_bounds__(256, 2) void k_flash(const unsigned short* __restrict__ qkv,
                                                  const unsigned short* __restrict__ vt,
                                                  unsigned short* __restrict__ aout) {
    __shared__ unsigned short Ks[2][8192];   // 64 keys x 128 hd, dbuf
    __shared__ unsigned short Vs[2][8192];   // 128 d x 64 keys, dbuf
    __shared__ unsigned short Plds[4][1152]; // per-wave 16 x 72
    const int wg = blockIdx.x;
    const int kvg = wg & 7;            // b*4+kvh -> pinned per XCD
    const int inner = wg >> 3;         // 0..63
    const int h_in = inner & 3;
    const int qt = inner >> 2;         // 0..15
    const int b = kvg >> 2, kvh = kvg & 3;
    const int h = kvh * 4 + h_in;
    const int tid = threadIdx.x;
    const int w = tid >> 6, lane = tid & 63;
    const int q = lane & 15, g = lane >> 4;
    const int qrow = qt * 128 + w * 32;

    short8 qf[2][4];
    #pragma unroll
    for (int u = 0; u < 2; ++u) {
        const unsigned short* Qp = qkv + (size_t)(b * 2048 + qrow + u * 16 + q) * 3072 + h * 128 + g * 8;
        #pragma unroll
        for (int t = 0; t < 4; ++t) qf[u][t] = *(const short8*)(Qp + t * 32);
    }

    const unsigned short* Kbase = qkv + (size_t)(b * 2048) * 3072 + 2048 + kvh * 128;
    const unsigned short* Vbase = vt + (size_t)((b * 4 + kvh) * 128) * 2048;
    const unsigned short* gK[4];
    const unsigned short* gV[4];
    #pragma unroll
    for (int i = 0; i < 4; ++i) {
        int rowK = w * 16 + i * 4 + (lane >> 4);
        gK[i] = Kbase + (size_t)rowK * 3072 + (((lane & 15) ^ (rowK & 7)) << 3);
        int rowV = w * 32 + i * 8 + (lane >> 3);
        gV[i] = Vbase + (size_t)rowV * 2048 + (((lane & 7) ^ (rowV & 7)) << 3);
    }

    const int swz = (q & 7) << 3;
    int tcK[4];
    #pragma unroll
    for (int t = 0; t < 4; ++t) tcK[t] = (t * 32 + g * 8) ^ swz;

    unsigned short* Pw = Plds[w];

    float m_run[2] = {-INFINITY, -INFINITY};
    float l_run[2] = {0.f, 0.f};
    f32x4 o[2][8];
    #pragma unroll
    for (int u = 0; u < 2; ++u)
        #pragma unroll
        for (int nf = 0; nf < 8; ++nf) o[u][nf] = (f32x4){0.f, 0.f, 0.f, 0.f};

    auto STAGE = [&](int buf) {
        #pragma unroll
        for (int i = 0; i < 4; ++i) {
            gload16(gK[i], &Ks[buf][w * 2048 + i * 512]);
            gload16(gV[i], &Vs[buf][w * 2048 + i * 512]);
            gK[i] += 64 * 3072;
            gV[i] += 64;
        }
    };

    STAGE(0);
    int cur = 0;
    for (int t0 = 0; t0 < 32; ++t0) {
        if (t0 > 0) __builtin_amdgcn_s_barrier();
        if (t0 + 1 < 32) {
            STAGE(cur ^ 1);
            asm volatile("s_waitcnt vmcnt(8)" ::: "memory");
        } else {
            asm volatile("s_waitcnt vmcnt(0)" ::: "memory");
        }
        __builtin_amdgcn_s_barrier();

        const unsigned short* Kt = Ks[cur];
        const unsigned short* Vt = Vs[cur];

        f32x4 st[2][4];
        #pragma unroll
        for (int ks = 0; ks < 4; ++ks) {
            f32x4 a0 = (f32x4){0.f, 0.f, 0.f, 0.f};
            f32x4 a1 = (f32x4){0.f, 0.f, 0.f, 0.f};
            int rb = (ks * 16 + q) * 128;
            #pragma unroll
            for (int t = 0; t < 4; ++t) {
                short8 kf = *(const short8*)&Kt[rb + tcK[t]];
                a0 = __builtin_amdgcn_mfma_f32_16x16x32_bf16(kf, qf[0][t], a0, 0, 0, 0);
                a1 = __builtin_amdgcn_mfma_f32_16x16x32_bf16(kf, qf[1][t], a1, 0, 0, 0);
            }
            st[0][ks] = a0; st[1][ks] = a1;
        }

        short8 vf[8][2];
        #pragma unroll
        for (int nf = 0; nf < 8; ++nf) {
            int rb = (nf * 16 + q) * 64;
            #pragma unroll
            for (int t = 0; t < 2; ++t) vf[nf][t] = *(const short8*)&Vt[rb + tcK[t]];
        }

        #pragma unroll
        for (int u = 0; u < 2; ++u) {
            float mx = fmaxf(
                fmaxf(fmaxf(fmaxf(st[u][0][0], st[u][0][1]), fmaxf(st[u][0][2], st[u][0][3])),
                      fmaxf(fmaxf(st[u][1][0], st[u][1][1]), fmaxf(st[u][1][2], st[u][1][3]))),
                fmaxf(fmaxf(fmaxf(st[u][2][0], st[u][2][1]), fmaxf(st[u][2][2], st[u][2][3])),
                      fmaxf(fmaxf(st[u][3][0], st[u][3][1]), fmaxf(st[u][3][2], st[u][3][3]))));
            mx = fmaxf(mx, __shfl_xor(mx, 16));
            mx = fmaxf(mx, __shfl_xor(mx, 32));
            if (__any(mx - m_run[u] > 8.0f)) {          // defer-max (exp2 domain)
                float mn = fmaxf(m_run[u], mx);
                float sc = exp2_fast(m_run[u] - mn);
                l_run[u] *= sc;
                f32x4 sv;
                #pragma unroll
                for (int rr = 0; rr < 4; ++rr) sv[rr] = __shfl(sc, 4 * g + rr);
                #pragma unroll
                for (int nf = 0; nf < 8; ++nf) o[u][nf] *= sv;
                m_run[u] = mn;
            }
            f32x4 pe[4];
            #pragma unroll
            for (int ks = 0; ks < 4; ++ks)
                #pragma unroll
                for (int rr = 0; rr < 4; ++rr) pe[ks][rr] = exp2_fast(st[u][ks][rr] - m_run[u]);
            f32x4 ls4 = (pe[0] + pe[1]) + (pe[2] + pe[3]);
            float ls = (ls4[0] + ls4[1]) + (ls4[2] + ls4[3]);
            ls += __shfl_xor(ls, 16);
            ls += __shfl_xor(ls, 32);
            l_run[u] += ls;

            #pragma unroll
            for (int ks = 0; ks < 4; ++ks) {
                uint2 pk;
                pk.x = cvt_pk_bf16(pe[ks][0], pe[ks][1]);
                pk.y = cvt_pk_bf16(pe[ks][2], pe[ks][3]);
                *(uint2*)&Pw[q * 72 + ks * 16 + 4 * g] = pk;
            }
            asm volatile("s_waitcnt lgkmcnt(0)" ::: "memory");
            short8 pa0 = *(const short8*)&Pw[q * 72 + g * 8];
            short8 pa1 = *(const short8*)&Pw[q * 72 + 32 + g * 8];

            #pragma unroll
            for (int nf = 0; nf < 8; ++nf) {
                f32x4 a = o[u][nf];
                a = __builtin_amdgcn_mfma_f32_16x16x32_bf16(pa0, vf[nf][0], a, 0, 0, 0);
                a = __builtin_amdgcn_mfma_f32_16x16x32_bf16(pa1, vf[nf][1], a, 0, 0, 0);
                o[u][nf] = a;
            }
        }
        cur ^= 1;
    }

    #pragma unroll
    for (int u = 0; u < 2; ++u) {
        f32x4 li;
        #pragma unroll
        for (int rr = 0; rr < 4; ++rr) li[rr] = __shfl(l_run[u], 4 * g + rr);
        #pragma unroll
        for (int rr = 0; rr < 4; ++rr) li[rr] = 1.0f / li[rr];
        #pragma unroll
        for (int nf = 0; nf < 8; ++nf)
            #pragma unroll
            for (int rr = 0; rr < 4; ++rr) {
                size_t row = (size_t)(b * 2048 + qrow + u * 16 + 4 * g + rr);
                aout[row * 2048 + h * 128 + nf * 16 + q] = f2bf(o[u][nf][rr] * li[rr]);
            }
    }
}

extern "C" void kernel_launch(void* const* d_in, const int* in_sizes, int n_in,
                              void* d_out, int out_size, void* d_ws, size_t ws_size,
                              hipStream_t stream) {
    (void)in_sizes; (void)n_in; (void)out_size; (void)ws_size;
    const float* hs = (const float*)d_in[0];
    const int* pos  = (const int*)d_in[1];
    const float* wq = (const float*)d_in[2];
    const float* wk = (const float*)d_in[3];
    const float* wv = (const float*)d_in[4];
    const float* wo = (const float*)d_in[5];
    float* out = (float*)d_out;

    unsigned short* hsb   = (unsigned short*)d_ws;              // 4096*2048
    unsigned short* wqkvb = hsb + (size_t)4096 * 2048;          // 3072*2048
    unsigned short* wob   = wqkvb + (size_t)3072 * 2048;        // 2048*2048
    unsigned short* qkvt  = wob + (size_t)2048 * 2048;          // 4096*3072 (q|k used)
    unsigned short* vtb   = qkvt + (size_t)4096 * 3072;         // 8*128*2048
    float2* tb            = (float2*)(vtb + (size_t)8 * 128 * 2048);   // 4096*64
    unsigned short* aoutb = (unsigned short*)(tb + (size_t)4096 * 64); // 4096*2048

    k_prep<<<19456, 256, 0, stream>>>(hs, wq, wk, wv, wo, pos, hsb, wqkvb, wob, tb);
    k_gemm<1><<<dim3(24, 32), 256, 0, stream>>>(hsb, wqkvb, nullptr, qkvt, vtb, tb, 4096, 3072, 2048);
    k_flash<<<dim3(512), 256, 0, stream>>>(qkvt, vtb, aoutb);
    k_gemm<0><<<dim3(16, 32), 256, 0, stream>>>(aoutb, wob, out, nullptr, nullptr, nullptr, 4096, 2048, 2048);
}